// Round 1
// baseline (5216.510 us; speedup 1.0000x reference)
//
#include <hip/hip_runtime.h>

// TrueEpisodicMemory: out[b,:] = softmax_m(q[b]·k[m] + 0.5*ctx[b]·mc[m] + exp(0.1*ts[m])) · V
// B=131072, M=100, D=1024, C=16.  Fused fp32 baseline (round 1).

constexpr int M_MEM  = 100;
constexpr int M_PAD  = 128;
constexpr int D_DIM  = 1024;
constexpr int C_DIM  = 16;
constexpr int ROWS   = 64;       // rows per block
constexpr int DC     = 32;       // d-chunk for QK phase
constexpr int QS     = 44;       // LDS row stride (floats): 44 -> conflict-free strided-m b128 reads
constexpr int SS     = 104;      // scores row stride

__global__ __launch_bounds__(256, 2)
void epmem_fused(const float* __restrict__ q,   // [B,1024]
                 const float* __restrict__ cx,  // [B,16]
                 const float* __restrict__ mk,  // [100,1024]
                 const float* __restrict__ mv,  // [100,1024]
                 const float* __restrict__ mc,  // [100,16]
                 const float* __restrict__ ts,  // [100]
                 float* __restrict__ out)       // [B,1024]
{
    __shared__ float Qc[ROWS][QS];    // 64*44
    __shared__ float Kc[M_PAD][QS];   // 128*44 (zero-padded m>=100)
    __shared__ float S[ROWS][SS];     // scores then attn

    const int t  = threadIdx.x;
    const int b0 = blockIdx.x * ROWS;
    const int rg = t >> 5;   // 0..7
    const int mg = t & 31;   // 0..31

    float acc[8][4];
    #pragma unroll
    for (int i = 0; i < 8; ++i)
        #pragma unroll
        for (int j = 0; j < 4; ++j) acc[i][j] = 0.f;

    // ---------- QK phase: 32 chunks of D, + 1 context chunk ----------
    for (int ch = 0; ch <= 32; ++ch) {
        __syncthreads();   // previous iter's readers done before restage
        if (ch < 32) {
            const int dbase = ch * DC;
            // stage Q chunk: 64 rows x 32 d = 512 float4, 2/thread
            #pragma unroll
            for (int it = 0; it < 2; ++it) {
                int i = t + it * 256;                  // 0..511
                int r = i >> 3, d4 = (i & 7) << 2;
                float4 v = *reinterpret_cast<const float4*>(&q[(size_t)(b0 + r) * D_DIM + dbase + d4]);
                *reinterpret_cast<float4*>(&Qc[r][d4]) = v;
            }
            // stage K chunk: 128 rows x 32 d = 1024 float4, 4/thread (zero pad m>=100)
            #pragma unroll
            for (int it = 0; it < 4; ++it) {
                int i = t + it * 256;                  // 0..1023
                int m = i >> 3, d4 = (i & 7) << 2;
                float4 v = make_float4(0.f, 0.f, 0.f, 0.f);
                if (m < M_MEM)
                    v = *reinterpret_cast<const float4*>(&mk[(size_t)m * D_DIM + dbase + d4]);
                *reinterpret_cast<float4*>(&Kc[m][d4]) = v;
            }
        } else {
            // context chunk: 16 wide, zero-pad cols 16..31; k' = 0.5*mem_contexts
            {
                int r = t >> 2, c4 = (t & 3) << 2;     // r 0..63
                float4 v = *reinterpret_cast<const float4*>(&cx[(size_t)(b0 + r) * C_DIM + c4]);
                *reinterpret_cast<float4*>(&Qc[r][c4]) = v;
                *reinterpret_cast<float4*>(&Qc[r][16 + c4]) = make_float4(0.f, 0.f, 0.f, 0.f);
            }
            #pragma unroll
            for (int it = 0; it < 2; ++it) {
                int i = t + it * 256;                  // 0..511 -> m 0..127
                int m = i >> 2, c4 = (i & 3) << 2;
                float4 v = make_float4(0.f, 0.f, 0.f, 0.f);
                if (m < M_MEM) {
                    v = *reinterpret_cast<const float4*>(&mc[(size_t)m * C_DIM + c4]);
                    v.x *= 0.5f; v.y *= 0.5f; v.z *= 0.5f; v.w *= 0.5f;
                }
                *reinterpret_cast<float4*>(&Kc[m][c4]) = v;
                *reinterpret_cast<float4*>(&Kc[m][16 + c4]) = make_float4(0.f, 0.f, 0.f, 0.f);
            }
        }
        __syncthreads();
        // compute: 8 rows (rg+8i) x 4 m (mg+32j) register tile
        #pragma unroll
        for (int d4 = 0; d4 < DC; d4 += 4) {
            float4 kv[4];
            #pragma unroll
            for (int j = 0; j < 4; ++j)
                kv[j] = *reinterpret_cast<const float4*>(&Kc[mg + 32 * j][d4]);
            #pragma unroll
            for (int i = 0; i < 8; ++i) {
                const float4 qv = *reinterpret_cast<const float4*>(&Qc[rg + 8 * i][d4]);
                #pragma unroll
                for (int j = 0; j < 4; ++j) {
                    acc[i][j] += qv.x * kv[j].x + qv.y * kv[j].y
                               + qv.z * kv[j].z + qv.w * kv[j].w;
                }
            }
        }
    }

    // ---------- epilogue: time-decay bias, write scores ----------
    __syncthreads();   // Qc/Kc dead; S may be written
    #pragma unroll
    for (int j = 0; j < 4; ++j) {
        int m = mg + 32 * j;
        if (m < M_MEM) {
            float dec = __expf(0.1f * ts[m]);   // exp(-TW*(CT - ts)) with CT=0, TW=0.1
            #pragma unroll
            for (int i = 0; i < 8; ++i)
                S[rg + 8 * i][m] = acc[i][j] + dec;
        }
    }
    __syncthreads();

    // ---------- softmax over m (rows on lanes of wave 0) ----------
    if (t < ROWS) {
        float mx = -1e30f;
        for (int m = 0; m < M_MEM; ++m) mx = fmaxf(mx, S[t][m]);
        float sum = 0.f;
        for (int m = 0; m < M_MEM; ++m) {
            float e = __expf(S[t][m] - mx);
            S[t][m] = e;
            sum += e;
        }
        float inv = 1.f / sum;
        for (int m = 0; m < M_MEM; ++m) S[t][m] *= inv;
    }
    __syncthreads();

    // ---------- PV phase: out[r][d] = sum_m attn[r][m] * V[m][d] ----------
    // V streamed from L2 (400 KB resident); attn broadcast from LDS.
    const int dc  = (t & 31) << 2;   // 32 cols * float4 = 128-wide d chunk
    const int rg2 = t >> 5;          // 8 row groups -> rows rg2+8i
    for (int db = 0; db < D_DIM; db += 128) {
        float4 o[8];
        #pragma unroll
        for (int i = 0; i < 8; ++i) o[i] = make_float4(0.f, 0.f, 0.f, 0.f);
        #pragma unroll 4
        for (int m = 0; m < M_MEM; ++m) {
            const float4 v = *reinterpret_cast<const float4*>(&mv[(size_t)m * D_DIM + db + dc]);
            #pragma unroll
            for (int i = 0; i < 8; ++i) {
                const float a = S[rg2 + 8 * i][m];
                o[i].x += a * v.x; o[i].y += a * v.y;
                o[i].z += a * v.z; o[i].w += a * v.w;
            }
        }
        #pragma unroll
        for (int i = 0; i < 8; ++i) {
            *reinterpret_cast<float4*>(&out[(size_t)(b0 + rg2 + 8 * i) * D_DIM + db + dc]) = o[i];
        }
    }
}

extern "C" void kernel_launch(void* const* d_in, const int* in_sizes, int n_in,
                              void* d_out, int out_size, void* d_ws, size_t ws_size,
                              hipStream_t stream) {
    const float* q  = (const float*)d_in[0];   // query [B,1024]
    const float* cx = (const float*)d_in[1];   // context [B,16]
    const float* mk = (const float*)d_in[2];   // mem_keys [100,1024]
    const float* mv = (const float*)d_in[3];   // mem_values [100,1024]
    const float* mc = (const float*)d_in[4];   // mem_contexts [100,16]
    const float* ts = (const float*)d_in[5];   // mem_timestamps [100]
    float* out = (float*)d_out;

    const int B = in_sizes[0] / D_DIM;         // 131072
    dim3 grid(B / ROWS), block(256);
    hipLaunchKernelGGL(epmem_fused, grid, block, 0, stream, q, cx, mk, mv, mc, ts, out);
}

// Round 2
// 542.913 us; speedup vs baseline: 9.6084x; 9.6084x over previous
//
#include <hip/hip_runtime.h>

// TrueEpisodicMemory round 2: MFMA split-bf16.
// out[b,:] = softmax_m(q[b]·mk[m] + 0.5*cx[b]·mc[m] + exp(0.1*ts[m])) · mv
// B=131072, M=100 (pad 112/128), D=1024, C=16.
// Prologue converts K (with ctx folded as k-cols 1024..1039) and V^T to split bf16 in d_ws.
// Main kernel: per wave 32 rows, 16x16x32 MFMA, 3-term split QK (hi*hi+hi*lo+lo*hi),
// in-register softmax, PV from transposed split-V. No LDS staging in K-loop.

typedef __attribute__((ext_vector_type(8))) short bf16x8;
typedef __attribute__((ext_vector_type(4))) float f32x4;

constexpr int DQ = 1024;
constexpr int CD = 16;
constexpr int MM = 100;
constexpr int KD = 1056;    // 1024 q-dims + 16 ctx + 16 zero
constexpr int MP = 128;     // padded M for PV
constexpr int NT = 7;       // 7 m-tiles of 16 -> 112 >= 100

// ws layout (bf16 elements): KH[112][1056], KL[112][1056], VH[1024][128], VL[1024][128]
constexpr size_t KE = (size_t)112 * KD;     // 118272
constexpr size_t VE = (size_t)DQ * MP;      // 131072
// total = 2*KE + 2*VE = 498688 elems = 997376 bytes

__device__ __forceinline__ unsigned short f2bf(float x) {
    unsigned u = __builtin_bit_cast(unsigned, x);
    u += 0x7fffu + ((u >> 16) & 1u);        // RNE to bf16
    return (unsigned short)(u >> 16);
}
__device__ __forceinline__ void split1(float x, unsigned short& h, unsigned short& l) {
    h = f2bf(x);
    float hf = __builtin_bit_cast(float, (unsigned)h << 16);
    l = f2bf(x - hf);
}

// ---------------- prologue: build split-bf16 K (ctx folded) ----------------
__global__ void build_k(const float* __restrict__ mk, const float* __restrict__ mc,
                        unsigned short* __restrict__ KH, unsigned short* __restrict__ KL)
{
    int d = blockIdx.x * 64 + threadIdx.x;
    int m = blockIdx.y;                      // 0..111
    if (d >= KD) return;
    float x = 0.f;
    if (m < MM) {
        if (d < DQ)            x = mk[(size_t)m * DQ + d];
        else if (d < DQ + CD)  x = 0.5f * mc[(size_t)m * CD + (d - DQ)];
    }
    unsigned short h, l;
    split1(x, h, l);
    KH[(size_t)m * KD + d] = h;
    KL[(size_t)m * KD + d] = l;
}

// ---------------- prologue: build split-bf16 V^T [1024][128] ----------------
__global__ void build_vt(const float* __restrict__ mv,
                         unsigned short* __restrict__ VH, unsigned short* __restrict__ VL)
{
    int idx = blockIdx.x * 256 + threadIdx.x;   // 0..131071
    int d = idx >> 7, m = idx & 127;
    float x = (m < MM) ? mv[(size_t)m * DQ + d] : 0.f;
    unsigned short h, l;
    split1(x, h, l);
    VH[idx] = h;   // VH[d][m]
    VL[idx] = l;
}

// ---------------- main fused kernel ----------------
__global__ __launch_bounds__(256, 4)
void epmem_mfma(const float* __restrict__ q, const float* __restrict__ cx,
                const float* __restrict__ ts,
                const unsigned short* __restrict__ KH, const unsigned short* __restrict__ KL,
                const unsigned short* __restrict__ VH, const unsigned short* __restrict__ VL,
                float* __restrict__ out)
{
    __shared__ unsigned short Pl[4][32][MP];    // per-wave P (attn) tile, 32 KB

    const int t    = threadIdx.x;
    const int w    = t >> 6;
    const int lane = t & 63;
    const int lr   = lane & 15;      // A-row / B-col / D-col lane index
    const int lk   = lane >> 4;      // k-group 0..3
    const int kcol = lk * 8;
    const int row0 = blockIdx.x * 128 + w * 32;

    const float* q0 = q  + (size_t)(row0 + lr)      * DQ;
    const float* q1 = q  + (size_t)(row0 + 16 + lr) * DQ;
    const float* c0 = cx + (size_t)(row0 + lr)      * CD;
    const float* c1 = cx + (size_t)(row0 + 16 + lr) * CD;

    f32x4 acc[2][NT];
    #pragma unroll
    for (int rt = 0; rt < 2; ++rt)
        #pragma unroll
        for (int nt = 0; nt < NT; ++nt) acc[rt][nt] = (f32x4){0.f, 0.f, 0.f, 0.f};

    // ---------- QK^T: 32 k-steps from q + 1 ctx k-step ----------
    for (int ks = 0; ks <= 32; ++ks) {
        const int kb = ks * 32 + kcol;
        float f0[8], f1[8];
        if (ks < 32) {
            float4 a = *(const float4*)(q0 + kb);
            float4 b = *(const float4*)(q0 + kb + 4);
            float4 c = *(const float4*)(q1 + kb);
            float4 d = *(const float4*)(q1 + kb + 4);
            f0[0]=a.x; f0[1]=a.y; f0[2]=a.z; f0[3]=a.w;
            f0[4]=b.x; f0[5]=b.y; f0[6]=b.z; f0[7]=b.w;
            f1[0]=c.x; f1[1]=c.y; f1[2]=c.z; f1[3]=c.w;
            f1[4]=d.x; f1[5]=d.y; f1[6]=d.z; f1[7]=d.w;
        } else {
            if (lk < 2) {   // ctx cols 0..15 live in k-groups 0,1
                float4 a = *(const float4*)(c0 + kcol);
                float4 b = *(const float4*)(c0 + kcol + 4);
                float4 c = *(const float4*)(c1 + kcol);
                float4 d = *(const float4*)(c1 + kcol + 4);
                f0[0]=a.x; f0[1]=a.y; f0[2]=a.z; f0[3]=a.w;
                f0[4]=b.x; f0[5]=b.y; f0[6]=b.z; f0[7]=b.w;
                f1[0]=c.x; f1[1]=c.y; f1[2]=c.z; f1[3]=c.w;
                f1[4]=d.x; f1[5]=d.y; f1[6]=d.z; f1[7]=d.w;
            } else {
                #pragma unroll
                for (int e = 0; e < 8; ++e) { f0[e] = 0.f; f1[e] = 0.f; }
            }
        }
        bf16x8 ah0, al0, ah1, al1;
        #pragma unroll
        for (int e = 0; e < 8; ++e) {
            unsigned short h, l;
            split1(f0[e], h, l); ah0[e] = (short)h; al0[e] = (short)l;
            split1(f1[e], h, l); ah1[e] = (short)h; al1[e] = (short)l;
        }
        #pragma unroll
        for (int nt = 0; nt < NT; ++nt) {
            const size_t ko = (size_t)(nt * 16 + lr) * KD + kb;
            bf16x8 bh = *(const bf16x8*)(KH + ko);
            bf16x8 bl = *(const bf16x8*)(KL + ko);
            acc[0][nt] = __builtin_amdgcn_mfma_f32_16x16x32_bf16(ah0, bh, acc[0][nt], 0, 0, 0);
            acc[1][nt] = __builtin_amdgcn_mfma_f32_16x16x32_bf16(ah1, bh, acc[1][nt], 0, 0, 0);
            acc[0][nt] = __builtin_amdgcn_mfma_f32_16x16x32_bf16(al0, bh, acc[0][nt], 0, 0, 0);
            acc[1][nt] = __builtin_amdgcn_mfma_f32_16x16x32_bf16(al1, bh, acc[1][nt], 0, 0, 0);
            acc[0][nt] = __builtin_amdgcn_mfma_f32_16x16x32_bf16(ah0, bl, acc[0][nt], 0, 0, 0);
            acc[1][nt] = __builtin_amdgcn_mfma_f32_16x16x32_bf16(ah1, bl, acc[1][nt], 0, 0, 0);
        }
    }

    // ---------- softmax, fully in-register ----------
    // acc[rt][nt][r] = S[row = 16*rt + 4*lk + r][m = 16*nt + lr]
    float dec[NT];
    #pragma unroll
    for (int nt = 0; nt < NT; ++nt) {
        int m = nt * 16 + lr;
        dec[nt] = (m < MM) ? __expf(0.1f * ts[m]) : 0.f;
    }
    #pragma unroll
    for (int rt = 0; rt < 2; ++rt) {
        float rm[4] = {-3e38f, -3e38f, -3e38f, -3e38f};
        #pragma unroll
        for (int nt = 0; nt < NT; ++nt) {
            int m = nt * 16 + lr;
            #pragma unroll
            for (int r = 0; r < 4; ++r) {
                float s = (m < MM) ? (acc[rt][nt][r] + dec[nt]) : -3e38f;
                acc[rt][nt][r] = s;
                rm[r] = fmaxf(rm[r], s);
            }
        }
        #pragma unroll
        for (int r = 0; r < 4; ++r)
            #pragma unroll
            for (int off = 1; off < 16; off <<= 1)
                rm[r] = fmaxf(rm[r], __shfl_xor(rm[r], off));
        float rs[4] = {0.f, 0.f, 0.f, 0.f};
        #pragma unroll
        for (int nt = 0; nt < NT; ++nt)
            #pragma unroll
            for (int r = 0; r < 4; ++r) {
                float e = __expf(acc[rt][nt][r] - rm[r]);
                acc[rt][nt][r] = e;
                rs[r] += e;
            }
        #pragma unroll
        for (int r = 0; r < 4; ++r)
            #pragma unroll
            for (int off = 1; off < 16; off <<= 1)
                rs[r] += __shfl_xor(rs[r], off);
        float inv[4];
        #pragma unroll
        for (int r = 0; r < 4; ++r) inv[r] = 1.f / rs[r];
        #pragma unroll
        for (int nt = 0; nt < NT; ++nt)
            #pragma unroll
            for (int r = 0; r < 4; ++r)
                Pl[w][16 * rt + 4 * lk + r][nt * 16 + lr] = f2bf(acc[rt][nt][r] * inv[r]);
    }
    // zero-pad P cols 112..127 (V^T rows there are zero too, but avoid NaN*0)
    {
        int rr = lane & 31;
        int cc = 112 + (lane >> 5) * 8;
        uint4 z = {0u, 0u, 0u, 0u};
        *(uint4*)&Pl[w][rr][cc] = z;
    }
    __syncthreads();

    // ---------- PV: out = P · V ----------
    bf16x8 pa[2][4];
    #pragma unroll
    for (int rt = 0; rt < 2; ++rt)
        #pragma unroll
        for (int ks = 0; ks < 4; ++ks)
            pa[rt][ks] = *(const bf16x8*)&Pl[w][16 * rt + lr][ks * 32 + kcol];

    #pragma unroll 2
    for (int nt2 = 0; nt2 < 64; ++nt2) {
        f32x4 o0 = {0.f, 0.f, 0.f, 0.f}, o1 = {0.f, 0.f, 0.f, 0.f};
        const size_t vb = (size_t)(nt2 * 16 + lr) * MP + kcol;
        #pragma unroll
        for (int ks = 0; ks < 4; ++ks) {
            bf16x8 vh = *(const bf16x8*)(VH + vb + ks * 32);
            bf16x8 vl = *(const bf16x8*)(VL + vb + ks * 32);
            o0 = __builtin_amdgcn_mfma_f32_16x16x32_bf16(pa[0][ks], vh, o0, 0, 0, 0);
            o1 = __builtin_amdgcn_mfma_f32_16x16x32_bf16(pa[1][ks], vh, o1, 0, 0, 0);
            o0 = __builtin_amdgcn_mfma_f32_16x16x32_bf16(pa[0][ks], vl, o0, 0, 0, 0);
            o1 = __builtin_amdgcn_mfma_f32_16x16x32_bf16(pa[1][ks], vl, o1, 0, 0, 0);
        }
        const int col = nt2 * 16 + lr;
        #pragma unroll
        for (int r = 0; r < 4; ++r) {
            out[(size_t)(row0 + 4 * lk + r) * DQ + col]      = o0[r];
            out[(size_t)(row0 + 16 + 4 * lk + r) * DQ + col] = o1[r];
        }
    }
}

extern "C" void kernel_launch(void* const* d_in, const int* in_sizes, int n_in,
                              void* d_out, int out_size, void* d_ws, size_t ws_size,
                              hipStream_t stream) {
    const float* q  = (const float*)d_in[0];   // [B,1024]
    const float* cx = (const float*)d_in[1];   // [B,16]
    const float* mk = (const float*)d_in[2];   // [100,1024]
    const float* mv = (const float*)d_in[3];   // [100,1024]
    const float* mc = (const float*)d_in[4];   // [100,16]
    const float* ts = (const float*)d_in[5];   // [100]
    float* out = (float*)d_out;

    unsigned short* wsp = (unsigned short*)d_ws;
    unsigned short* KH = wsp;
    unsigned short* KL = wsp + KE;
    unsigned short* VH = wsp + 2 * KE;
    unsigned short* VL = wsp + 2 * KE + VE;

    const int B = in_sizes[0] / DQ;            // 131072

    build_k<<<dim3(17, 112), dim3(64), 0, stream>>>(mk, mc, KH, KL);
    build_vt<<<dim3(512), dim3(256), 0, stream>>>(mv, VH, VL);
    epmem_mfma<<<dim3(B / 128), dim3(256), 0, stream>>>(q, cx, ts, KH, KL, VH, VL, out);
}

// Round 3
// 384.137 us; speedup vs baseline: 13.5798x; 1.4133x over previous
//
#include <hip/hip_runtime.h>

// TrueEpisodicMemory round 3: fp16 MFMA (A split hi/lo, K/V single fp16) + non-temporal
// streaming hints on q/out to keep K/V L2-resident.
// out[b,:] = softmax_m(q[b]·mk[m] + 0.5*cx[b]·mc[m] + exp(0.1*ts[m])) · mv
// B=131072, M=100 (pad 112/128), D=1024, C=16.

typedef __attribute__((ext_vector_type(8))) _Float16 f16x8;
typedef __attribute__((ext_vector_type(4))) float f32x4;

constexpr int DQ = 1024;
constexpr int CD = 16;
constexpr int MM = 100;
constexpr int KD = 1056;    // 1024 q-dims + 16 ctx + 16 zero
constexpr int MP = 128;     // padded M for PV
constexpr int NT = 7;       // 7 m-tiles of 16 -> 112 >= 100

// ws layout (fp16 elements): KH[112][1056], VH[1024][128]
constexpr size_t KE = (size_t)112 * KD;     // 118272
constexpr size_t VE = (size_t)DQ * MP;      // 131072

__device__ __forceinline__ void splith(float x, _Float16& h, _Float16& l) {
    h = (_Float16)x;
    l = (_Float16)(x - (float)h);
}

// ---------------- prologue: fp16 K (ctx folded at cols 1024..1039) ----------------
__global__ void build_k(const float* __restrict__ mk, const float* __restrict__ mc,
                        _Float16* __restrict__ KH)
{
    int d = blockIdx.x * 64 + threadIdx.x;
    int m = blockIdx.y;                      // 0..111
    if (d >= KD) return;
    float x = 0.f;
    if (m < MM) {
        if (d < DQ)            x = mk[(size_t)m * DQ + d];
        else if (d < DQ + CD)  x = 0.5f * mc[(size_t)m * CD + (d - DQ)];
    }
    KH[(size_t)m * KD + d] = (_Float16)x;
}

// ---------------- prologue: fp16 V^T [1024][128] ----------------
__global__ void build_vt(const float* __restrict__ mv, _Float16* __restrict__ VH)
{
    int idx = blockIdx.x * 256 + threadIdx.x;   // 0..131071
    int d = idx >> 7, m = idx & 127;
    float x = (m < MM) ? mv[(size_t)m * DQ + d] : 0.f;
    VH[idx] = (_Float16)x;   // VH[d][m]
}

// ---------------- main fused kernel ----------------
__global__ __launch_bounds__(256, 4)
void epmem_mfma(const float* __restrict__ q, const float* __restrict__ cx,
                const float* __restrict__ ts,
                const _Float16* __restrict__ KH, const _Float16* __restrict__ VH,
                float* __restrict__ out)
{
    __shared__ _Float16 Pl[4][32][MP];    // per-wave attn tile, 32 KB

    const int t    = threadIdx.x;
    const int w    = t >> 6;
    const int lane = t & 63;
    const int lr   = lane & 15;      // A-row / B-col / D-col lane index
    const int lk   = lane >> 4;      // k-group 0..3
    const int kcol = lk * 8;
    const int row0 = blockIdx.x * 128 + w * 32;

    const float* q0 = q  + (size_t)(row0 + lr)      * DQ;
    const float* q1 = q  + (size_t)(row0 + 16 + lr) * DQ;
    const float* c0 = cx + (size_t)(row0 + lr)      * CD;
    const float* c1 = cx + (size_t)(row0 + 16 + lr) * CD;

    f32x4 acc[2][NT];
    #pragma unroll
    for (int rt = 0; rt < 2; ++rt)
        #pragma unroll
        for (int nt = 0; nt < NT; ++nt) acc[rt][nt] = (f32x4){0.f, 0.f, 0.f, 0.f};

    // ---------- QK^T: 32 k-steps from q + 1 ctx k-step ----------
    for (int ks = 0; ks <= 32; ++ks) {
        const int kb = ks * 32 + kcol;
        float f0[8], f1[8];
        if (ks < 32) {
            f32x4 a = __builtin_nontemporal_load((const f32x4*)(q0 + kb));
            f32x4 b = __builtin_nontemporal_load((const f32x4*)(q0 + kb + 4));
            f32x4 c = __builtin_nontemporal_load((const f32x4*)(q1 + kb));
            f32x4 d = __builtin_nontemporal_load((const f32x4*)(q1 + kb + 4));
            #pragma unroll
            for (int e = 0; e < 4; ++e) {
                f0[e] = a[e]; f0[4 + e] = b[e];
                f1[e] = c[e]; f1[4 + e] = d[e];
            }
        } else {
            if (lk < 2) {   // ctx cols 0..15 live in k-groups 0,1
                f32x4 a = __builtin_nontemporal_load((const f32x4*)(c0 + kcol));
                f32x4 b = __builtin_nontemporal_load((const f32x4*)(c0 + kcol + 4));
                f32x4 c = __builtin_nontemporal_load((const f32x4*)(c1 + kcol));
                f32x4 d = __builtin_nontemporal_load((const f32x4*)(c1 + kcol + 4));
                #pragma unroll
                for (int e = 0; e < 4; ++e) {
                    f0[e] = a[e]; f0[4 + e] = b[e];
                    f1[e] = c[e]; f1[4 + e] = d[e];
                }
            } else {
                #pragma unroll
                for (int e = 0; e < 8; ++e) { f0[e] = 0.f; f1[e] = 0.f; }
            }
        }
        f16x8 ah0, al0, ah1, al1;
        #pragma unroll
        for (int e = 0; e < 8; ++e) {
            _Float16 h, l;
            splith(f0[e], h, l); ah0[e] = h; al0[e] = l;
            splith(f1[e], h, l); ah1[e] = h; al1[e] = l;
        }
        #pragma unroll
        for (int nt = 0; nt < NT; ++nt) {
            const size_t ko = (size_t)(nt * 16 + lr) * KD + kb;
            f16x8 bh = *(const f16x8*)(KH + ko);
            acc[0][nt] = __builtin_amdgcn_mfma_f32_16x16x32_f16(ah0, bh, acc[0][nt], 0, 0, 0);
            acc[1][nt] = __builtin_amdgcn_mfma_f32_16x16x32_f16(ah1, bh, acc[1][nt], 0, 0, 0);
            acc[0][nt] = __builtin_amdgcn_mfma_f32_16x16x32_f16(al0, bh, acc[0][nt], 0, 0, 0);
            acc[1][nt] = __builtin_amdgcn_mfma_f32_16x16x32_f16(al1, bh, acc[1][nt], 0, 0, 0);
        }
    }

    // ---------- softmax, fully in-register ----------
    // acc[rt][nt][r] = S[row = 16*rt + 4*lk + r][m = 16*nt + lr]
    float dec[NT];
    #pragma unroll
    for (int nt = 0; nt < NT; ++nt) {
        int m = nt * 16 + lr;
        dec[nt] = (m < MM) ? __expf(0.1f * ts[m]) : 0.f;
    }
    #pragma unroll
    for (int rt = 0; rt < 2; ++rt) {
        float rm[4] = {-3e38f, -3e38f, -3e38f, -3e38f};
        #pragma unroll
        for (int nt = 0; nt < NT; ++nt) {
            int m = nt * 16 + lr;
            #pragma unroll
            for (int r = 0; r < 4; ++r) {
                float s = (m < MM) ? (acc[rt][nt][r] + dec[nt]) : -3e38f;
                acc[rt][nt][r] = s;
                rm[r] = fmaxf(rm[r], s);
            }
        }
        #pragma unroll
        for (int r = 0; r < 4; ++r)
            #pragma unroll
            for (int off = 1; off < 16; off <<= 1)
                rm[r] = fmaxf(rm[r], __shfl_xor(rm[r], off));
        float rs[4] = {0.f, 0.f, 0.f, 0.f};
        #pragma unroll
        for (int nt = 0; nt < NT; ++nt)
            #pragma unroll
            for (int r = 0; r < 4; ++r) {
                float e = __expf(acc[rt][nt][r] - rm[r]);
                acc[rt][nt][r] = e;
                rs[r] += e;
            }
        #pragma unroll
        for (int r = 0; r < 4; ++r)
            #pragma unroll
            for (int off = 1; off < 16; off <<= 1)
                rs[r] += __shfl_xor(rs[r], off);
        float inv[4];
        #pragma unroll
        for (int r = 0; r < 4; ++r) inv[r] = 1.f / rs[r];
        #pragma unroll
        for (int nt = 0; nt < NT; ++nt)
            #pragma unroll
            for (int r = 0; r < 4; ++r)
                Pl[w][16 * rt + 4 * lk + r][nt * 16 + lr] = (_Float16)(acc[rt][nt][r] * inv[r]);
    }
    // zero-pad P cols 112..127
    {
        int rr = lane & 31;
        int cc = 112 + (lane >> 5) * 8;
        uint4 z = {0u, 0u, 0u, 0u};
        *(uint4*)&Pl[w][rr][cc] = z;
    }
    __syncthreads();

    // ---------- PV: out = P · V ----------
    f16x8 pa[2][4];
    #pragma unroll
    for (int rt = 0; rt < 2; ++rt)
        #pragma unroll
        for (int ks = 0; ks < 4; ++ks)
            pa[rt][ks] = *(const f16x8*)&Pl[w][16 * rt + lr][ks * 32 + kcol];

    #pragma unroll 2
    for (int nt2 = 0; nt2 < 64; ++nt2) {
        f32x4 o0 = {0.f, 0.f, 0.f, 0.f}, o1 = {0.f, 0.f, 0.f, 0.f};
        const size_t vb = (size_t)(nt2 * 16 + lr) * MP + kcol;
        #pragma unroll
        for (int ks = 0; ks < 4; ++ks) {
            f16x8 vh = *(const f16x8*)(VH + vb + ks * 32);
            o0 = __builtin_amdgcn_mfma_f32_16x16x32_f16(pa[0][ks], vh, o0, 0, 0, 0);
            o1 = __builtin_amdgcn_mfma_f32_16x16x32_f16(pa[1][ks], vh, o1, 0, 0, 0);
        }
        const int col = nt2 * 16 + lr;
        #pragma unroll
        for (int r = 0; r < 4; ++r) {
            __builtin_nontemporal_store(o0[r], &out[(size_t)(row0 + 4 * lk + r) * DQ + col]);
            __builtin_nontemporal_store(o1[r], &out[(size_t)(row0 + 16 + 4 * lk + r) * DQ + col]);
        }
    }
}

extern "C" void kernel_launch(void* const* d_in, const int* in_sizes, int n_in,
                              void* d_out, int out_size, void* d_ws, size_t ws_size,
                              hipStream_t stream) {
    const float* q  = (const float*)d_in[0];   // [B,1024]
    const float* cx = (const float*)d_in[1];   // [B,16]
    const float* mk = (const float*)d_in[2];   // [100,1024]
    const float* mv = (const float*)d_in[3];   // [100,1024]
    const float* mc = (const float*)d_in[4];   // [100,16]
    const float* ts = (const float*)d_in[5];   // [100]
    float* out = (float*)d_out;

    _Float16* wsp = (_Float16*)d_ws;
    _Float16* KH = wsp;
    _Float16* VH = wsp + KE;

    const int B = in_sizes[0] / DQ;            // 131072

    build_k<<<dim3(17, 112), dim3(64), 0, stream>>>(mk, mc, KH);
    build_vt<<<dim3(512), dim3(256), 0, stream>>>(mv, VH);
    epmem_mfma<<<dim3(B / 128), dim3(256), 0, stream>>>(q, cx, ts, KH, VH, out);
}

// Round 4
// 340.447 us; speedup vs baseline: 15.3225x; 1.1283x over previous
//
#include <hip/hip_runtime.h>

// TrueEpisodicMemory round 4: m97-style pipelined LDS staging via global_load_lds.
// out[b,:] = softmax_m(q[b]·mk[m] + 0.5*cx[b]·mc[m] + exp(0.1*ts[m])) · mv
// B=131072, M=100 (pad 112/128), D=1024, C=16.
// Block: 128 q-rows, 4 waves (32 rows each). QK: 33 k-chunks of 32 (chunk 32 = ctx),
// Q[128][32]f32 + K[112][32]f16 double-buffered in LDS, staged with global_load_lds,
// 1 barrier/step. Softmax in-register. PV: V^T pre-padded [1024][144]f16 in ws,
// staged in [32][144] chunks, 32 steps. A-operands split fp16 hi/lo (3-term QK).

typedef __attribute__((ext_vector_type(8))) _Float16 f16x8;
typedef __attribute__((ext_vector_type(4))) float f32x4;

constexpr int DQ = 1024, CD = 16, MM = 100, KD = 1056, NT = 7;
constexpr int VROW = 144;                       // padded V^T row (fp16), 288B = 16 mod 128
constexpr size_t KE  = (size_t)112 * KD;        // KH elems
constexpr size_t VTE = (size_t)DQ * VROW;       // VT elems

// LDS layout (bytes), regions unioned across phases:
//   A [0, 32768):      Qb[2][128][32]f32 (16384 ea)   |  Pb[4][32][128]f16 (8192/wave)
//   B [32768, 51200):  Kb[2][112][32]f16 (7168 ea)    |  Vb[2][32][144]f16 (9216 ea)
constexpr int LDSZ = 51200, QBUF = 16384, KOFF = 32768, KBUF = 7168, VBUF = 9216, PW = 8192;

__device__ __forceinline__ void gl16(const void* g, void* l) {
    __builtin_amdgcn_global_load_lds(
        (const __attribute__((address_space(1))) unsigned int*)g,
        (__attribute__((address_space(3))) unsigned int*)l, 16, 0, 0);
}

// ---------------- prologue: fp16 K [112][1056], ctx folded at cols 1024..1039 ----------------
__global__ void build_k(const float* __restrict__ mk, const float* __restrict__ mc,
                        _Float16* __restrict__ KH)
{
    int d = blockIdx.x * 64 + threadIdx.x;
    int m = blockIdx.y;                      // 0..111
    if (d >= KD) return;
    float x = 0.f;
    if (m < MM) {
        if (d < DQ)            x = mk[(size_t)m * DQ + d];
        else if (d < DQ + CD)  x = 0.5f * mc[(size_t)m * CD + (d - DQ)];
    }
    KH[(size_t)m * KD + d] = (_Float16)x;
}

// ---------------- prologue: fp16 V^T [1024][144] (cols 100..143 zero) ----------------
__global__ void build_vt(const float* __restrict__ mv, _Float16* __restrict__ VT)
{
    int d = blockIdx.x;            // 0..1023
    int m = threadIdx.x;           // 0..255
    if (m < VROW)
        VT[(size_t)d * VROW + m] = (m < MM) ? (_Float16)mv[(size_t)m * DQ + d] : (_Float16)0.f;
}

// ---------------- main fused kernel ----------------
__global__ __launch_bounds__(256, 3)
void epmem_pipe(const float* __restrict__ q, const float* __restrict__ cx,
                const float* __restrict__ ts,
                const _Float16* __restrict__ KH, const _Float16* __restrict__ VT,
                float* __restrict__ out)
{
    __shared__ __align__(16) char lds[LDSZ];

    const int t = threadIdx.x, w = t >> 6, lane = t & 63;
    const int lr = lane & 15, lk = lane >> 4;
    const int row0 = blockIdx.x * 128;

    // ---- staging helpers (global_load_lds; dest = wave-uniform base, HW adds lane*16) ----
    auto stageQ = [&](int buf, int ks) {            // [128][32] f32, 1024 segs
        char* dst = lds + buf * QBUF;
        #pragma unroll
        for (int rd = 0; rd < 4; ++rd) {
            int s = rd * 256 + w * 64 + lane;       // seg: row s>>3, col (s&7)*4 floats
            gl16(q + (size_t)(row0 + (s >> 3)) * DQ + ks * 32 + (s & 7) * 4,
                 dst + (rd * 256 + w * 64) * 16);
        }
    };
    auto stageQctx = [&](int buf) {                 // packed [128][16] f32, 512 segs
        char* dst = lds + buf * QBUF;
        #pragma unroll
        for (int rd = 0; rd < 2; ++rd) {
            int s = rd * 256 + w * 64 + lane;       // row s>>2, col (s&3)*4
            gl16(cx + (size_t)(row0 + (s >> 2)) * CD + (s & 3) * 4,
                 dst + (rd * 256 + w * 64) * 16);
        }
    };
    auto stageK = [&](int buf, int ks) {            // [112][32] f16, 448 segs
        char* dst = lds + KOFF + buf * KBUF;
        {
            int s = w * 64 + lane;                  // row s>>2, col (s&3)*8 f16
            gl16(KH + (size_t)(s >> 2) * KD + ks * 32 + (s & 3) * 8, dst + (w * 64) * 16);
        }
        if (w < 3) {
            int s = 256 + w * 64 + lane;
            gl16(KH + (size_t)(s >> 2) * KD + ks * 32 + (s & 3) * 8, dst + (256 + w * 64) * 16);
        }
    };
    auto stageV = [&](int buf, int c) {             // [32][144] f16, contiguous 9216 B, 576 segs
        char* dst = lds + KOFF + buf * VBUF;
        const char* src = (const char*)(VT + (size_t)c * 32 * VROW);
        for (int rd = w; rd < 9; rd += 4)
            gl16(src + (rd * 64 + lane) * 16, dst + rd * 1024);
    };

    f32x4 acc[2][NT];
    #pragma unroll
    for (int rt = 0; rt < 2; ++rt)
        #pragma unroll
        for (int nt = 0; nt < NT; ++nt) acc[rt][nt] = (f32x4){0.f, 0.f, 0.f, 0.f};

    // ---------- QK^T pipeline: 33 chunk-steps ----------
    stageQ(0, 0); stageK(0, 0);
    asm volatile("s_waitcnt vmcnt(0)" ::: "memory");
    __syncthreads();
    int cur = 0;
    for (int ks = 0; ks <= 32; ++ks) {
        if (ks < 32) {                              // prefetch next chunk into buf^1
            if (ks + 1 == 32) stageQctx(cur ^ 1); else stageQ(cur ^ 1, ks + 1);
            stageK(cur ^ 1, ks + 1);
        }
        // A-fragments: read f32 from LDS, split to fp16 hi/lo
        f16x8 ah[2], al[2];
        if (ks < 32) {
            #pragma unroll
            for (int rt = 0; rt < 2; ++rt) {
                const float* qr = (const float*)(lds + cur * QBUF)
                                + (w * 32 + rt * 16 + lr) * 32 + lk * 8;
                f32x4 x = *(const f32x4*)qr, y = *(const f32x4*)(qr + 4);
                #pragma unroll
                for (int e = 0; e < 4; ++e) {
                    _Float16 h = (_Float16)x[e]; ah[rt][e] = h;     al[rt][e] = (_Float16)(x[e] - (float)h);
                    h = (_Float16)y[e];          ah[rt][4 + e] = h; al[rt][4 + e] = (_Float16)(y[e] - (float)h);
                }
            }
        } else {
            #pragma unroll
            for (int rt = 0; rt < 2; ++rt) {
                if (lk < 2) {
                    const float* qr = (const float*)(lds + cur * QBUF)
                                    + (w * 32 + rt * 16 + lr) * 16 + lk * 8;
                    f32x4 x = *(const f32x4*)qr, y = *(const f32x4*)(qr + 4);
                    #pragma unroll
                    for (int e = 0; e < 4; ++e) {
                        _Float16 h = (_Float16)x[e]; ah[rt][e] = h;     al[rt][e] = (_Float16)(x[e] - (float)h);
                        h = (_Float16)y[e];          ah[rt][4 + e] = h; al[rt][4 + e] = (_Float16)(y[e] - (float)h);
                    }
                } else {
                    #pragma unroll
                    for (int e = 0; e < 8; ++e) { ah[rt][e] = (_Float16)0.f; al[rt][e] = (_Float16)0.f; }
                }
            }
        }
        #pragma unroll
        for (int nt = 0; nt < NT; ++nt) {
            f16x8 bh = *(const f16x8*)(lds + KOFF + cur * KBUF + ((nt * 16 + lr) * 32 + lk * 8) * 2);
            acc[0][nt] = __builtin_amdgcn_mfma_f32_16x16x32_f16(ah[0], bh, acc[0][nt], 0, 0, 0);
            acc[0][nt] = __builtin_amdgcn_mfma_f32_16x16x32_f16(al[0], bh, acc[0][nt], 0, 0, 0);
            acc[1][nt] = __builtin_amdgcn_mfma_f32_16x16x32_f16(ah[1], bh, acc[1][nt], 0, 0, 0);
            acc[1][nt] = __builtin_amdgcn_mfma_f32_16x16x32_f16(al[1], bh, acc[1][nt], 0, 0, 0);
        }
        asm volatile("s_waitcnt vmcnt(0)" ::: "memory");
        __syncthreads();
        cur ^= 1;
    }

    // ---------- stage V chunk 0 early (region B free after final QK barrier) ----------
    stageV(0, 0);

    // ---------- softmax, fully in-register ----------
    // acc[rt][nt][r] = S[row = w*32 + 16rt + 4lk + r][m = 16nt + lr]
    float dec[NT];
    #pragma unroll
    for (int nt = 0; nt < NT; ++nt) {
        int m = nt * 16 + lr;
        dec[nt] = (m < MM) ? __expf(0.1f * ts[m]) : 0.f;
    }
    _Float16* Pw = (_Float16*)(lds + w * PW);
    #pragma unroll
    for (int rt = 0; rt < 2; ++rt) {
        float rm[4] = {-3e38f, -3e38f, -3e38f, -3e38f};
        #pragma unroll
        for (int nt = 0; nt < NT; ++nt) {
            int m = nt * 16 + lr;
            #pragma unroll
            for (int r = 0; r < 4; ++r) {
                float s = (m < MM) ? (acc[rt][nt][r] + dec[nt]) : -3e38f;
                acc[rt][nt][r] = s;
                rm[r] = fmaxf(rm[r], s);
            }
        }
        #pragma unroll
        for (int r = 0; r < 4; ++r)
            #pragma unroll
            for (int off = 1; off < 16; off <<= 1)
                rm[r] = fmaxf(rm[r], __shfl_xor(rm[r], off));
        float rs[4] = {0.f, 0.f, 0.f, 0.f};
        #pragma unroll
        for (int nt = 0; nt < NT; ++nt)
            #pragma unroll
            for (int r = 0; r < 4; ++r) {
                float e = __expf(acc[rt][nt][r] - rm[r]);
                acc[rt][nt][r] = e;
                rs[r] += e;
            }
        #pragma unroll
        for (int r = 0; r < 4; ++r)
            #pragma unroll
            for (int off = 1; off < 16; off <<= 1)
                rs[r] += __shfl_xor(rs[r], off);
        float inv[4];
        #pragma unroll
        for (int r = 0; r < 4; ++r) inv[r] = 1.f / rs[r];
        #pragma unroll
        for (int nt = 0; nt < NT; ++nt)
            #pragma unroll
            for (int r = 0; r < 4; ++r)
                Pw[(16 * rt + 4 * lk + r) * 128 + nt * 16 + lr] = (_Float16)(acc[rt][nt][r] * inv[r]);
    }
    {   // zero-pad P cols 112..127
        int row = lane & 31, half = lane >> 5;
        uint4 z = {0u, 0u, 0u, 0u};
        *(uint4*)(lds + w * PW + (row * 128 + 112 + half * 8) * 2) = z;
    }
    asm volatile("s_waitcnt vmcnt(0)" ::: "memory");
    __syncthreads();

    // ---------- PV pipeline: 32 d-chunk steps ----------
    f16x8 pa[2][4];
    #pragma unroll
    for (int rt = 0; rt < 2; ++rt)
        #pragma unroll
        for (int k4 = 0; k4 < 4; ++k4)
            pa[rt][k4] = *(const f16x8*)(lds + w * PW + ((rt * 16 + lr) * 128 + k4 * 32 + lk * 8) * 2);

    cur = 0;
    for (int c = 0; c < 32; ++c) {
        if (c < 31) stageV(cur ^ 1, c + 1);
        f32x4 o[2][2];
        #pragma unroll
        for (int rt = 0; rt < 2; ++rt)
            #pragma unroll
            for (int n2 = 0; n2 < 2; ++n2) o[rt][n2] = (f32x4){0.f, 0.f, 0.f, 0.f};
        #pragma unroll
        for (int k4 = 0; k4 < 4; ++k4) {
            #pragma unroll
            for (int n2 = 0; n2 < 2; ++n2) {
                f16x8 bv = *(const f16x8*)(lds + KOFF + cur * VBUF
                              + ((n2 * 16 + lr) * VROW + k4 * 32 + lk * 8) * 2);
                o[0][n2] = __builtin_amdgcn_mfma_f32_16x16x32_f16(pa[0][k4], bv, o[0][n2], 0, 0, 0);
                o[1][n2] = __builtin_amdgcn_mfma_f32_16x16x32_f16(pa[1][k4], bv, o[1][n2], 0, 0, 0);
            }
        }
        #pragma unroll
        for (int rt = 0; rt < 2; ++rt)
            #pragma unroll
            for (int n2 = 0; n2 < 2; ++n2) {
                const int col = c * 32 + n2 * 16 + lr;
                #pragma unroll
                for (int r = 0; r < 4; ++r)
                    out[(size_t)(row0 + w * 32 + rt * 16 + 4 * lk + r) * DQ + col] = o[rt][n2][r];
            }
        asm volatile("s_waitcnt vmcnt(0)" ::: "memory");
        __syncthreads();
        cur ^= 1;
    }
}

extern "C" void kernel_launch(void* const* d_in, const int* in_sizes, int n_in,
                              void* d_out, int out_size, void* d_ws, size_t ws_size,
                              hipStream_t stream) {
    const float* q  = (const float*)d_in[0];   // [B,1024]
    const float* cx = (const float*)d_in[1];   // [B,16]
    const float* mk = (const float*)d_in[2];   // [100,1024]
    const float* mv = (const float*)d_in[3];   // [100,1024]
    const float* mc = (const float*)d_in[4];   // [100,16]
    const float* ts = (const float*)d_in[5];   // [100]
    float* out = (float*)d_out;

    _Float16* wsp = (_Float16*)d_ws;
    _Float16* KH = wsp;                        // [112][1056]
    _Float16* VT = wsp + KE;                   // [1024][144]

    const int B = in_sizes[0] / DQ;            // 131072

    build_k<<<dim3(17, 112), dim3(64), 0, stream>>>(mk, mc, KH);
    build_vt<<<dim3(1024), dim3(256), 0, stream>>>(mv, VT);
    epmem_pipe<<<dim3(B / 128), dim3(256), 0, stream>>>(q, cx, ts, KH, VT, out);
}

// Round 5
// 306.032 us; speedup vs baseline: 17.0456x; 1.1125x over previous
//
#include <hip/hip_runtime.h>

// TrueEpisodicMemory round 5: counted-vmcnt pipeline (T4), 3-deep staging, Q-tile XOR swizzle.
// out[b,:] = softmax_m(q[b]·mk[m] + 0.5*cx[b]·mc[m] + exp(0.1*ts[m])) · mv
// B=131072, M=100 (pad 112/128), D=1024, C=16.
// Block: 128 q-rows, 4 waves. QK: 33 k-chunks of 32 (chunk 32 = ctx), Q[128][32]f32 +
// K[112][32]f16 triple-buffered via global_load_lds, ONE barrier/step, vmcnt never 0 in loop.
// Q LDS slot-swizzled (slot ^= (row>>1)&3) via pre-swizzled global source (rule #21).
// Softmax in-register. PV: V^T [1024][144]f16 staged [32][144] x3-deep, counted vmcnt(16+L).

typedef __attribute__((ext_vector_type(8))) _Float16 f16x8;
typedef __attribute__((ext_vector_type(4))) float f32x4;

constexpr int DQ = 1024, CD = 16, MM = 100, KD = 1056, NT = 7;
constexpr int VROW = 144;                       // padded V^T row (fp16)
constexpr size_t KE = (size_t)112 * KD;

// LDS layout (bytes). QK phase: Q[3][128][32]f32 @0, K[3][112][32]f16 @49152.
// PV phase (overlays): P[4][32][128]f16 @0, V[3][32][144]f16 @43008.
constexpr int QBUF = 16384, KOFF = 49152, KBUF = 7168;
constexpr int VOFF = 43008, VBUF = 9216, PW = 8192;
constexpr int LDSZ = 70656;

#define WAITV(n) asm volatile("s_waitcnt vmcnt(" #n ")" ::: "memory")

__device__ __forceinline__ void gl16(const void* g, void* l) {
    __builtin_amdgcn_global_load_lds(
        (const __attribute__((address_space(1))) unsigned int*)g,
        (__attribute__((address_space(3))) unsigned int*)l, 16, 0, 0);
}

// ---------------- prologue: fp16 K [112][1056], ctx folded at cols 1024..1039 ----------------
__global__ void build_k(const float* __restrict__ mk, const float* __restrict__ mc,
                        _Float16* __restrict__ KH)
{
    int d = blockIdx.x * 64 + threadIdx.x;
    int m = blockIdx.y;
    if (d >= KD) return;
    float x = 0.f;
    if (m < MM) {
        if (d < DQ)            x = mk[(size_t)m * DQ + d];
        else if (d < DQ + CD)  x = 0.5f * mc[(size_t)m * CD + (d - DQ)];
    }
    KH[(size_t)m * KD + d] = (_Float16)x;
}

// ---------------- prologue: fp16 V^T [1024][144] (cols 100..143 zero) ----------------
__global__ void build_vt(const float* __restrict__ mv, _Float16* __restrict__ VT)
{
    int d = blockIdx.x;
    int m = threadIdx.x;
    if (m < VROW)
        VT[(size_t)d * VROW + m] = (m < MM) ? (_Float16)mv[(size_t)m * DQ + d] : (_Float16)0.f;
}

// ---------------- main fused kernel ----------------
__global__ __launch_bounds__(256, 2)
void epmem_pipe(const float* __restrict__ q, const float* __restrict__ cx,
                const float* __restrict__ ts,
                const _Float16* __restrict__ KH, const _Float16* __restrict__ VT,
                float* __restrict__ out)
{
    __shared__ __align__(16) char lds[LDSZ];

    const int t = threadIdx.x, w = t >> 6, lane = t & 63;
    const int lr = lane & 15, lk = lane >> 4;
    const int row0 = blockIdx.x * 128;

    // ---- staging (global_load_lds: LDS dest = wave-uniform base + lane*16) ----
    auto stageQ = [&](int buf, int ks) {            // [128][32] f32, slot-swizzled source
        char* dst = lds + buf * QBUF;
        #pragma unroll
        for (int rd = 0; rd < 4; ++rd) {
            int s = rd * 256 + w * 64 + lane;       // seg: row s>>3, slot s&7
            int slotg = (s & 7) ^ ((s >> 4) & 3);   // pre-swizzle global col-chunk
            gl16(q + (size_t)(row0 + (s >> 3)) * DQ + ks * 32 + slotg * 4,
                 dst + (rd * 256 + w * 64) * 16);
        }
    };
    auto stageQctx = [&](int buf) {                 // packed [128][16] f32, no swizzle
        char* dst = lds + buf * QBUF;
        #pragma unroll
        for (int rd = 0; rd < 2; ++rd) {
            int s = rd * 256 + w * 64 + lane;       // row s>>2, slot s&3
            gl16(cx + (size_t)(row0 + (s >> 2)) * CD + (s & 3) * 4,
                 dst + (rd * 256 + w * 64) * 16);
        }
    };
    auto stageK = [&](int buf, int ks) {            // [112][32] f16 (structurally optimal banks)
        char* dst = lds + KOFF + buf * KBUF;
        {
            int s = w * 64 + lane;
            gl16(KH + (size_t)(s >> 2) * KD + ks * 32 + (s & 3) * 8, dst + (w * 64) * 16);
        }
        if (w < 3) {
            int s = 256 + w * 64 + lane;
            gl16(KH + (size_t)(s >> 2) * KD + ks * 32 + (s & 3) * 8, dst + (256 + w * 64) * 16);
        }
    };
    auto stageV = [&](int buf, int c) {             // [32][144] f16, contiguous 9216 B
        char* dst = lds + VOFF + buf * VBUF;
        const char* src = (const char*)(VT + (size_t)c * 32 * VROW);
        for (int rd = w; rd < 9; rd += 4)
            gl16(src + (rd * 64 + lane) * 16, dst + rd * 1024);
    };

    f32x4 acc[2][NT];
    #pragma unroll
    for (int rt = 0; rt < 2; ++rt)
        #pragma unroll
        for (int nt = 0; nt < NT; ++nt) acc[rt][nt] = (f32x4){0.f, 0.f, 0.f, 0.f};

    // ---------- QK^T: 33 chunk-steps, 3-deep pipeline ----------
    stageQ(0, 0); stageK(0, 0);
    stageQ(1, 1); stageK(1, 1);
    if (w < 3) { WAITV(6); } else { WAITV(5); }     // chunk 0 resident; chunk 1 in flight
    __builtin_amdgcn_s_barrier();

    int bc = 0, bs = 2;                             // current / stage buffer (mod 3)
    for (int ks = 0; ks <= 32; ++ks) {
        if (ks + 2 <= 32) {                         // prefetch chunk ks+2, depth 2
            if (ks + 2 == 32) stageQctx(bs); else stageQ(bs, ks + 2);
            stageK(bs, ks + 2);
        }
        // A-fragments from LDS (swizzled slots), split fp16 hi/lo
        const char* qb = lds + bc * QBUF;
        f16x8 ah[2], al[2];
        if (ks < 32) {
            const int g = (lr >> 1) & 3;
            #pragma unroll
            for (int rt = 0; rt < 2; ++rt) {
                const char* base = qb + (w * 32 + rt * 16 + lr) * 128;
                f32x4 x = *(const f32x4*)(base + (((2 * lk)     ^ g) << 4));
                f32x4 y = *(const f32x4*)(base + (((2 * lk + 1) ^ g) << 4));
                #pragma unroll
                for (int e = 0; e < 4; ++e) {
                    _Float16 h = (_Float16)x[e]; ah[rt][e] = h;     al[rt][e] = (_Float16)(x[e] - (float)h);
                    h = (_Float16)y[e];          ah[rt][4 + e] = h; al[rt][4 + e] = (_Float16)(y[e] - (float)h);
                }
            }
        } else {
            #pragma unroll
            for (int rt = 0; rt < 2; ++rt) {
                if (lk < 2) {
                    const float* qr = (const float*)qb + (w * 32 + rt * 16 + lr) * 16 + lk * 8;
                    f32x4 x = *(const f32x4*)qr, y = *(const f32x4*)(qr + 4);
                    #pragma unroll
                    for (int e = 0; e < 4; ++e) {
                        _Float16 h = (_Float16)x[e]; ah[rt][e] = h;     al[rt][e] = (_Float16)(x[e] - (float)h);
                        h = (_Float16)y[e];          ah[rt][4 + e] = h; al[rt][4 + e] = (_Float16)(y[e] - (float)h);
                    }
                } else {
                    #pragma unroll
                    for (int e = 0; e < 8; ++e) { ah[rt][e] = (_Float16)0.f; al[rt][e] = (_Float16)0.f; }
                }
            }
        }
        #pragma unroll
        for (int nt = 0; nt < NT; ++nt) {
            f16x8 bh = *(const f16x8*)(lds + KOFF + bc * KBUF + ((nt * 16 + lr) * 32 + lk * 8) * 2);
            acc[0][nt] = __builtin_amdgcn_mfma_f32_16x16x32_f16(ah[0], bh, acc[0][nt], 0, 0, 0);
            acc[0][nt] = __builtin_amdgcn_mfma_f32_16x16x32_f16(al[0], bh, acc[0][nt], 0, 0, 0);
            acc[1][nt] = __builtin_amdgcn_mfma_f32_16x16x32_f16(ah[1], bh, acc[1][nt], 0, 0, 0);
            acc[1][nt] = __builtin_amdgcn_mfma_f32_16x16x32_f16(al[1], bh, acc[1][nt], 0, 0, 0);
        }
        // counted waits: chunk ks+1 must be resident before next iter; never drain in-loop
        if (ks < 30)       { if (w < 3) { WAITV(6); } else { WAITV(5); } }
        else if (ks == 30) { if (w < 3) { WAITV(4); } else { WAITV(3); } }   // ctx stage is smaller
        else if (ks == 31) { WAITV(0); }
        if (ks < 32) __builtin_amdgcn_s_barrier();
        bc = (bc == 2) ? 0 : bc + 1;
        bs = (bs == 2) ? 0 : bs + 1;
    }

    // ---------- transition: all waves done with QK LDS before V staging overlays it ----------
    asm volatile("" ::: "memory");
    __builtin_amdgcn_s_barrier();
    stageV(0, 0); stageV(1, 1);                     // V latency hides under softmax

    // ---------- softmax, fully in-register ----------
    float dec[NT];
    #pragma unroll
    for (int nt = 0; nt < NT; ++nt) {
        int m = nt * 16 + lr;
        dec[nt] = (m < MM) ? __expf(0.1f * ts[m]) : 0.f;
    }
    _Float16* Pw = (_Float16*)(lds + w * PW);
    #pragma unroll
    for (int rt = 0; rt < 2; ++rt) {
        float rm[4] = {-3e38f, -3e38f, -3e38f, -3e38f};
        #pragma unroll
        for (int nt = 0; nt < NT; ++nt) {
            int m = nt * 16 + lr;
            #pragma unroll
            for (int r = 0; r < 4; ++r) {
                float s = (m < MM) ? (acc[rt][nt][r] + dec[nt]) : -3e38f;
                acc[rt][nt][r] = s;
                rm[r] = fmaxf(rm[r], s);
            }
        }
        #pragma unroll
        for (int r = 0; r < 4; ++r)
            #pragma unroll
            for (int off = 1; off < 16; off <<= 1)
                rm[r] = fmaxf(rm[r], __shfl_xor(rm[r], off));
        float rs[4] = {0.f, 0.f, 0.f, 0.f};
        #pragma unroll
        for (int nt = 0; nt < NT; ++nt)
            #pragma unroll
            for (int r = 0; r < 4; ++r) {
                float e = __expf(acc[rt][nt][r] - rm[r]);
                acc[rt][nt][r] = e;
                rs[r] += e;
            }
        #pragma unroll
        for (int r = 0; r < 4; ++r)
            #pragma unroll
            for (int off = 1; off < 16; off <<= 1)
                rs[r] += __shfl_xor(rs[r], off);
        float inv[4];
        #pragma unroll
        for (int r = 0; r < 4; ++r) inv[r] = 1.f / rs[r];
        #pragma unroll
        for (int nt = 0; nt < NT; ++nt)
            #pragma unroll
            for (int r = 0; r < 4; ++r)
                Pw[(16 * rt + 4 * lk + r) * 128 + nt * 16 + lr] = (_Float16)(acc[rt][nt][r] * inv[r]);
    }
    {   // zero-pad P cols 112..127
        int row = lane & 31, half = lane >> 5;
        uint4 z = {0u, 0u, 0u, 0u};
        *(uint4*)(lds + w * PW + (row * 128 + 112 + half * 8) * 2) = z;
    }
    if (w == 0) { WAITV(3); } else { WAITV(2); }    // V chunk 0 resident; chunk 1 in flight
    __builtin_amdgcn_s_barrier();

    // ---------- PV: 32 d-chunk steps, 3-deep, counted vmcnt(16 stores + L loads) ----------
    f16x8 pa[2][4];
    #pragma unroll
    for (int rt = 0; rt < 2; ++rt)
        #pragma unroll
        for (int k4 = 0; k4 < 4; ++k4)
            pa[rt][k4] = *(const f16x8*)(lds + w * PW + ((rt * 16 + lr) * 128 + k4 * 32 + lk * 8) * 2);

    int vc = 0, vs = 2;
    for (int c = 0; c < 32; ++c) {
        if (c + 2 < 32) stageV(vs, c + 2);
        f32x4 o[2][2];
        #pragma unroll
        for (int rt = 0; rt < 2; ++rt)
            #pragma unroll
            for (int n2 = 0; n2 < 2; ++n2) o[rt][n2] = (f32x4){0.f, 0.f, 0.f, 0.f};
        #pragma unroll
        for (int k4 = 0; k4 < 4; ++k4) {
            #pragma unroll
            for (int n2 = 0; n2 < 2; ++n2) {
                f16x8 bv = *(const f16x8*)(lds + VOFF + vc * VBUF
                              + ((n2 * 16 + lr) * VROW + k4 * 32 + lk * 8) * 2);
                o[0][n2] = __builtin_amdgcn_mfma_f32_16x16x32_f16(pa[0][k4], bv, o[0][n2], 0, 0, 0);
                o[1][n2] = __builtin_amdgcn_mfma_f32_16x16x32_f16(pa[1][k4], bv, o[1][n2], 0, 0, 0);
            }
        }
        #pragma unroll
        for (int rt = 0; rt < 2; ++rt)
            #pragma unroll
            for (int n2 = 0; n2 < 2; ++n2) {
                const int col = c * 32 + n2 * 16 + lr;
                #pragma unroll
                for (int r = 0; r < 4; ++r)
                    out[(size_t)(row0 + w * 32 + rt * 16 + 4 * lk + r) * DQ + col] = o[rt][n2][r];
            }
        if (c < 30)       { if (w == 0) { WAITV(19); } else { WAITV(18); } }
        else if (c == 30) { WAITV(16); }
        if (c < 31) __builtin_amdgcn_s_barrier();
        vc = (vc == 2) ? 0 : vc + 1;
        vs = (vs == 2) ? 0 : vs + 1;
    }
}

extern "C" void kernel_launch(void* const* d_in, const int* in_sizes, int n_in,
                              void* d_out, int out_size, void* d_ws, size_t ws_size,
                              hipStream_t stream) {
    const float* q  = (const float*)d_in[0];
    const float* cx = (const float*)d_in[1];
    const float* mk = (const float*)d_in[2];
    const float* mv = (const float*)d_in[3];
    const float* mc = (const float*)d_in[4];
    const float* ts = (const float*)d_in[5];
    float* out = (float*)d_out;

    _Float16* wsp = (_Float16*)d_ws;
    _Float16* KH = wsp;                        // [112][1056]
    _Float16* VT = wsp + KE;                   // [1024][144]

    const int B = in_sizes[0] / DQ;            // 131072

    build_k<<<dim3(17, 112), dim3(64), 0, stream>>>(mk, mc, KH);
    build_vt<<<dim3(1024), dim3(256), 0, stream>>>(mv, VT);
    epmem_pipe<<<dim3(B / 128), dim3(256), 0, stream>>>(q, cx, ts, KH, VT, out);
}